// Round 1
// baseline (405.802 us; speedup 1.0000x reference)
//
#include <hip/hip_runtime.h>

// MakeCutouts: out[(n*B+b), c, i, j] = x[b, c, oy[n] + i*sz[n]/224, ox[n] + j*sz[n]/224]
// B=16, C=3, H=W=512, CUTN=32, CUT_SIZE=224. Output fp32, 308 MB -> write-bound.

#define CUT_SIZE 224
#define CUTN     32
#define BATCH    16
#define CHAN     3
#define HEIGHT   512
#define WIDTH    512
#define J4       (CUT_SIZE / 4)   // 56 float4 per output row

__global__ __launch_bounds__(256) void make_cutouts_kernel(
    const float* __restrict__ x,
    const int*   __restrict__ sizes,
    const int*   __restrict__ offsetx,
    const int*   __restrict__ offsety,
    float4*      __restrict__ out,
    int total_vec4)
{
    int v = blockIdx.x * blockDim.x + threadIdx.x;
    if (v >= total_vec4) return;

    // Decompose flat vec4 index: innermost j4, then i, then c, then (n*B+b).
    int j4 = v % J4;
    int t  = v / J4;
    int i  = t % CUT_SIZE;
    t /= CUT_SIZE;
    int c  = t % CHAN;
    t /= CHAN;
    int b  = t % BATCH;
    int n  = t / BATCH;

    const int sz = sizes[n];
    const int ox = offsetx[n];
    const int oy = offsety[n];

    // i*sz <= 223*512 fits in 24 bits; / 224 lowers to magic multiply.
    const int yy = oy + (i * sz) / CUT_SIZE;
    const int j0 = j4 * 4;
    const int x0 = ox + ((j0 + 0) * sz) / CUT_SIZE;
    const int x1 = ox + ((j0 + 1) * sz) / CUT_SIZE;
    const int x2 = ox + ((j0 + 2) * sz) / CUT_SIZE;
    const int x3 = ox + ((j0 + 3) * sz) / CUT_SIZE;

    const float* __restrict__ row =
        x + ((size_t)((b * CHAN + c) * HEIGHT + yy)) * WIDTH;

    float4 r;
    r.x = row[x0];
    r.y = row[x1];
    r.z = row[x2];
    r.w = row[x3];
    out[v] = r;  // coalesced: consecutive lanes -> consecutive 16B
}

extern "C" void kernel_launch(void* const* d_in, const int* in_sizes, int n_in,
                              void* d_out, int out_size, void* d_ws, size_t ws_size,
                              hipStream_t stream) {
    const float* x       = (const float*)d_in[0];
    const int*   sizes   = (const int*)d_in[1];
    const int*   offsetx = (const int*)d_in[2];
    const int*   offsety = (const int*)d_in[3];
    float4*      out     = (float4*)d_out;

    const int total_vec4 = CUTN * BATCH * CHAN * CUT_SIZE * J4;  // 19,267,584
    const int block = 256;
    const int grid  = (total_vec4 + block - 1) / block;          // 75,264

    make_cutouts_kernel<<<grid, block, 0, stream>>>(x, sizes, offsetx, offsety,
                                                    out, total_vec4);
}